// Round 3
// baseline (1065.862 us; speedup 1.0000x reference)
//
#include <hip/hip_runtime.h>
#include <stdint.h>

#define EPS_VAL 2.220446049250313e-16f

typedef unsigned short u16;
typedef __bf16 bf16x8 __attribute__((ext_vector_type(8)));
typedef float f32x4 __attribute__((ext_vector_type(4)));

static __device__ __forceinline__ u16 f2bf(float v) {
    __bf16 b = (__bf16)v;
    return __builtin_bit_cast(u16, b);
}
static __device__ __forceinline__ float bf2f(u16 u) {
    __bf16 b = __builtin_bit_cast(__bf16, u);
    return (float)b;
}
static __device__ __forceinline__ void gll16(const void* g, void* l) {
    __builtin_amdgcn_global_load_lds(
        (const __attribute__((address_space(1))) unsigned int*)g,
        (__attribute__((address_space(3))) unsigned int*)l, 16, 0, 0);
}

// ---------------- transpose + convert: in [R][C] f32 -> out [C][R] bf16 ----------------
__global__ void k_transpose_cvt(const float* __restrict__ in, u16* __restrict__ out,
                                int R, int C) {
    __shared__ float t[32][33];
    const float* ip = in + (size_t)blockIdx.z * R * C;
    u16* op = out + (size_t)blockIdx.z * R * C;
    int tx = threadIdx.x & 31, ty = threadIdx.x >> 5;
    int c = blockIdx.x * 32 + tx;
    #pragma unroll
    for (int i = 0; i < 4; ++i) {
        int r = blockIdx.y * 32 + ty + i * 8;
        t[ty + i * 8][tx] = ip[(size_t)r * C + c];
    }
    __syncthreads();
    int r2 = blockIdx.y * 32 + tx;
    #pragma unroll
    for (int i = 0; i < 4; ++i) {
        int c2 = blockIdx.x * 32 + ty + i * 8;
        op[(size_t)c2 * R + r2] = f2bf(t[tx][ty + i * 8]);
    }
}

// ------- gating (fused x->bf16): logits, top-2, softmax, expert lists, xb -------
__global__ void k_gate(const float* __restrict__ x, const float* __restrict__ wg,
                       u16* __restrict__ xb, int* __restrict__ cnt,
                       uint2* __restrict__ asg, float4* __restrict__ rec) {
    int row  = blockIdx.x * 4 + (threadIdx.x >> 6);
    int lane = threadIdx.x & 63;
    const float4* px = (const float4*)(x + (size_t)row * 512) + lane * 2;
    float4 v0 = px[0], v1 = px[1];
    union { u16 h[8]; uint4 u; } o;
    o.h[0]=f2bf(v0.x); o.h[1]=f2bf(v0.y); o.h[2]=f2bf(v0.z); o.h[3]=f2bf(v0.w);
    o.h[4]=f2bf(v1.x); o.h[5]=f2bf(v1.y); o.h[6]=f2bf(v1.z); o.h[7]=f2bf(v1.w);
    ((uint4*)(xb + (size_t)row * 512))[lane] = o.u;

    float xv[8] = {v0.x, v0.y, v0.z, v0.w, v1.x, v1.y, v1.z, v1.w};
    float a0=0,a1=0,a2=0,a3=0,a4=0,a5=0,a6=0,a7=0;
    const float4* wp = (const float4*)wg + (size_t)lane * 16;
    #pragma unroll
    for (int j = 0; j < 8; ++j) {
        float4 wa = wp[j * 2], wb = wp[j * 2 + 1];
        float v = xv[j];
        a0 += v*wa.x; a1 += v*wa.y; a2 += v*wa.z; a3 += v*wa.w;
        a4 += v*wb.x; a5 += v*wb.y; a6 += v*wb.z; a7 += v*wb.w;
    }
    #pragma unroll
    for (int off = 32; off; off >>= 1) {
        a0 += __shfl_xor(a0, off); a1 += __shfl_xor(a1, off);
        a2 += __shfl_xor(a2, off); a3 += __shfl_xor(a3, off);
        a4 += __shfl_xor(a4, off); a5 += __shfl_xor(a5, off);
        a6 += __shfl_xor(a6, off); a7 += __shfl_xor(a7, off);
    }
    if (lane == 0) {
        float v[8] = {a0,a1,a2,a3,a4,a5,a6,a7};
        int i0 = 0;
        #pragma unroll
        for (int e = 1; e < 8; ++e) if (v[e] > v[i0]) i0 = e;
        int i1 = (i0 == 0) ? 1 : 0;
        #pragma unroll
        for (int e = 0; e < 8; ++e) if (e != i0 && v[e] > v[i1]) i1 = e;
        float ex = expf(v[i1] - v[i0]);
        float g0 = 1.f / (1.f + ex), g1 = ex / (1.f + ex);
        rec[row] = make_float4(__int_as_float(i0), __int_as_float(i1), g0, g1);
        if (i0 != 7) {
            int p = atomicAdd(&cnt[i0], 1);
            asg[i0 * 16384 + p] = make_uint2((unsigned)(row << 1), __float_as_uint(g0));
        }
        if (i1 != 7) {
            int p = atomicAdd(&cnt[i1], 1);
            asg[i1 * 16384 + p] = make_uint2((unsigned)((row << 1) | 1), __float_as_uint(g1));
        }
    }
}

// ------- fused per-expert MLP: 8 waves, BM=64, HB=32, 2 blocks/CU target -------
// LDS map (byte offsets in smem):
//   [0,32768)      W1s [32 rows][64 slots*16B], slot swizzle: slot ^ (row&7)
//                  (also Xs [64][64 slots] staging area spanning [0,65536))
//   [32768,65536)  W2s [512 d][4 slots*16B],    slot swizzle: slot ^ (d&3)
//   [65536,73728)  Hp  [2 kh][8 tile][4 reg][64 lane] u16 (bf16 partials)
//   [73728,77824)  Hs  [64 row][64 B], byte swizzle: ^ ((row&3)<<4)
//   [77824,78080)  rsl[64] int ; [78080,78336) gl[64] float
__global__ __launch_bounds__(512, 4) void k_expert(
    const u16* __restrict__ xb,
    const u16* __restrict__ w1t,   // [7][2048][512] bf16 (W1^T)
    const u16* __restrict__ w2t,   // [7][512][2048] bf16 (W2^T)
    const float* __restrict__ b1,
    const float* __restrict__ b2,
    const int* __restrict__ cnt,
    const uint2* __restrict__ asg,
    u16* __restrict__ ybuf)        // [2][16384][512] bf16
{
    __shared__ __attribute__((aligned(16))) char smem[78336];
    u16*   Hp  = (u16*)(smem + 65536);
    int*   rsl = (int*)(smem + 77824);
    float* gl  = (float*)(smem + 78080);

    const int e    = blockIdx.y;
    const int base = blockIdx.x * 64;
    const int ce   = cnt[e];
    if (base >= ce) return;

    const int tid = threadIdx.x;
    if (tid < 64) {
        int idx = base + tid;
        if (idx < ce) {
            uint2 a = asg[e * 16384 + idx];
            rsl[tid] = (int)a.x;
            gl[tid]  = __builtin_bit_cast(float, a.y);
        } else { rsl[tid] = -1; gl[tid] = 0.f; }
    }
    __syncthreads();

    // stage X rows (64 x 512 bf16) into [0,65536) with slot^(row&7) swizzle
    {
        int row = tid >> 3;
        int s0  = (tid & 7) * 8;
        int rs  = rsl[row];
        const u16* src = xb + (size_t)((rs < 0) ? 0 : (rs >> 1)) * 512;
        #pragma unroll
        for (int j = 0; j < 8; ++j) {
            int s = s0 + j;
            uint4 v = *(const uint4*)(src + s * 8);
            *(uint4*)(smem + row * 1024 + ((s ^ (row & 7)) * 16)) = v;
        }
    }
    __syncthreads();

    const int w    = tid >> 6;     // 0..7
    const int lane = tid & 63;
    const int l16  = lane & 15;
    const int q    = lane >> 4;    // 0..3
    const int rg   = w & 3;        // phase-1 row group
    const int kh   = w >> 2;       // phase-1 K half

    // hoist A fragments: rows rg*16+l16, K-half kh (256 wide)
    bf16x8 xa[8];
    {
        int xrow = rg * 16 + l16;
        #pragma unroll
        for (int kk = 0; kk < 8; ++kk) {
            int slot = kh * 32 + kk * 4 + q;
            xa[kk] = *(const bf16x8*)(smem + xrow * 1024 + 16 * (slot ^ (xrow & 7)));
        }
    }

    f32x4 acc[4][4];
    #pragma unroll
    for (int mt = 0; mt < 4; ++mt)
        #pragma unroll
        for (int nt = 0; nt < 4; ++nt) acc[mt][nt] = (f32x4){0.f, 0.f, 0.f, 0.f};

    const u16* w1p = w1t + (size_t)e * 2048 * 512;
    const u16* w2p = w2t + (size_t)e * 512 * 2048;

    for (int hc = 0; hc < 2048; hc += 32) {
        __syncthreads();   // prior-chunk phase-2 reads (or xa hoist) complete

        // stage W1^T chunk rows 0..31 (1 KB each) via global_load_lds,
        // source pre-swizzled so linear LDS dest yields slot^(row&7) layout
        #pragma unroll
        for (int i = 0; i < 4; ++i) {
            int row = w * 4 + i;
            gll16(w1p + (size_t)(hc + row) * 512 + (lane ^ (row & 7)) * 8,
                  smem + row * 1024);
        }
        // stage W2^T chunk: 512 rows x 64 B; 16 rows per instruction
        #pragma unroll
        for (int i = 0; i < 4; ++i) {
            int d0 = (w * 4 + i) * 16;
            int d  = d0 + (lane >> 2), s = lane & 3;
            gll16(w2p + (size_t)d * 2048 + hc + ((s ^ (d & 3)) * 8),
                  smem + 32768 + d0 * 64);
        }
        __syncthreads();   // staging visible (vmcnt drained by barrier)

        // phase 1: partial H for (rg, kh), both 16-col groups
        f32x4 h0a = (f32x4){0.f,0.f,0.f,0.f}, h1a = (f32x4){0.f,0.f,0.f,0.f};
        __builtin_amdgcn_s_setprio(1);
        #pragma unroll
        for (int kk = 0; kk < 8; ++kk) {
            int slot = kh * 32 + kk * 4 + q;
            int sw   = slot ^ (l16 & 7);          // row&7 == l16&7 for both rows
            bf16x8 b0 = *(const bf16x8*)(smem + l16 * 1024 + 16 * sw);
            bf16x8 b1f= *(const bf16x8*)(smem + (16 + l16) * 1024 + 16 * sw);
            h0a = __builtin_amdgcn_mfma_f32_16x16x32_bf16(xa[kk], b0,  h0a, 0, 0, 0);
            h1a = __builtin_amdgcn_mfma_f32_16x16x32_bf16(xa[kk], b1f, h1a, 0, 0, 0);
        }
        __builtin_amdgcn_s_setprio(0);
        #pragma unroll
        for (int r = 0; r < 4; ++r) {
            Hp[((kh * 8 + rg    ) * 4 + r) * 64 + lane] = f2bf(h0a[r]);
            Hp[((kh * 8 + rg + 4) * 4 + r) * 64 + lane] = f2bf(h1a[r]);
        }
        __syncthreads();   // Hp complete

        // combine: 512 threads, each 4 h at one row -> relu -> Hs (bf16)
        {
            int row = tid >> 3, hh = (tid & 7) * 4;
            int tile = (row >> 4) + 4 * (hh >> 4);
            int reg  = row & 3;
            int lp   = (hh & 15) + 16 * ((row >> 2) & 3);
            const u16* p0 = &Hp[((    tile) * 4 + reg) * 64 + lp];
            const u16* p1 = &Hp[((8 + tile) * 4 + reg) * 64 + lp];
            ushort4 ua = *(const ushort4*)p0;
            ushort4 ub = *(const ushort4*)p1;
            float4 bv = *(const float4*)(b1 + e * 2048 + hc + hh);
            u16 ov[4];
            float v0 = bf2f(ua.x) + bf2f(ub.x) + bv.x; ov[0] = f2bf(v0 > 0.f ? v0 : 0.f);
            float v1 = bf2f(ua.y) + bf2f(ub.y) + bv.y; ov[1] = f2bf(v1 > 0.f ? v1 : 0.f);
            float v2 = bf2f(ua.z) + bf2f(ub.z) + bv.z; ov[2] = f2bf(v2 > 0.f ? v2 : 0.f);
            float v3 = bf2f(ua.w) + bf2f(ub.w) + bv.w; ov[3] = f2bf(v3 > 0.f ? v3 : 0.f);
            *(uint2*)(smem + 73728 + row * 64 + ((hh * 2) ^ ((row & 3) << 4))) =
                *(uint2*)ov;
        }
        __syncthreads();   // Hs complete

        // phase 2: acc += H(64x32) @ W2chunk(32 x 64-col slice per wave)
        bf16x8 af[4];
        #pragma unroll
        for (int mt = 0; mt < 4; ++mt) {
            int row = mt * 16 + l16;
            af[mt] = *(const bf16x8*)(smem + 73728 + row * 64 +
                                      ((16 * q) ^ ((row & 3) << 4)));
        }
        __builtin_amdgcn_s_setprio(1);
        #pragma unroll
        for (int nt = 0; nt < 4; ++nt) {
            int d = w * 64 + nt * 16 + l16;
            bf16x8 bm = *(const bf16x8*)(smem + 32768 + d * 64 + 16 * (q ^ (d & 3)));
            acc[0][nt] = __builtin_amdgcn_mfma_f32_16x16x32_bf16(af[0], bm, acc[0][nt], 0, 0, 0);
            acc[1][nt] = __builtin_amdgcn_mfma_f32_16x16x32_bf16(af[1], bm, acc[1][nt], 0, 0, 0);
            acc[2][nt] = __builtin_amdgcn_mfma_f32_16x16x32_bf16(af[2], bm, acc[2][nt], 0, 0, 0);
            acc[3][nt] = __builtin_amdgcn_mfma_f32_16x16x32_bf16(af[3], bm, acc[3][nt], 0, 0, 0);
        }
        __builtin_amdgcn_s_setprio(0);
    }

    // epilogue: ybuf[slot][row][d] = bf16(g * (acc + b2))
    #pragma unroll
    for (int nt = 0; nt < 4; ++nt) {
        int d = w * 64 + nt * 16 + l16;
        float b2v = b2[e * 512 + d];
        #pragma unroll
        for (int mt = 0; mt < 4; ++mt) {
            #pragma unroll
            for (int r = 0; r < 4; ++r) {
                int m = mt * 16 + q * 4 + r;
                int rs = rsl[m];
                if (rs >= 0) {
                    ybuf[((size_t)(rs & 1) * 16384 + (rs >> 1)) * 512 + d] =
                        f2bf(gl[m] * (acc[mt][nt][r] + b2v));
                }
            }
        }
    }
}

// ---------------- final combine + EPS replacement ----------------
__global__ void k_final(const float* __restrict__ x, const float4* __restrict__ rec,
                        const u16* __restrict__ ybuf, float* __restrict__ out) {
    int i = blockIdx.x * 256 + threadIdx.x;
    int row = i >> 7;
    float4 r = rec[row];
    int e0 = __float_as_int(r.x), e1 = __float_as_int(r.y);
    float g7 = (e0 == 7) ? r.z : ((e1 == 7) ? r.w : 0.f);
    float4 xv = ((const float4*)x)[i];
    float o0 = g7 * xv.x, o1 = g7 * xv.y, o2 = g7 * xv.z, o3 = g7 * xv.w;
    size_t off = (size_t)i * 4;
    if (e0 != 7) {
        uint2 y = *(const uint2*)(ybuf + off);
        o0 += bf2f((u16)(y.x & 0xffff)); o1 += bf2f((u16)(y.x >> 16));
        o2 += bf2f((u16)(y.y & 0xffff)); o3 += bf2f((u16)(y.y >> 16));
    }
    if (e1 != 7) {
        uint2 y = *(const uint2*)(ybuf + 8388608 + off);
        o0 += bf2f((u16)(y.x & 0xffff)); o1 += bf2f((u16)(y.x >> 16));
        o2 += bf2f((u16)(y.y & 0xffff)); o3 += bf2f((u16)(y.y >> 16));
    }
    float4 res;
    res.x = (o0 == 0.f) ? EPS_VAL : o0;
    res.y = (o1 == 0.f) ? EPS_VAL : o1;
    res.z = (o2 == 0.f) ? EPS_VAL : o2;
    res.w = (o3 == 0.f) ? EPS_VAL : o3;
    ((float4*)out)[i] = res;
}

extern "C" void kernel_launch(void* const* d_in, const int* in_sizes, int n_in,
                              void* d_out, int out_size, void* d_ws, size_t ws_size,
                              hipStream_t stream) {
    const float* x  = (const float*)d_in[0];
    const float* wg = (const float*)d_in[1];
    const float* W1 = (const float*)d_in[2];
    const float* b1 = (const float*)d_in[3];
    const float* W2 = (const float*)d_in[4];
    const float* b2 = (const float*)d_in[5];

    char* ws = (char*)d_ws;
    int*    cnt  = (int*)ws;
    float4* rec  = (float4*)(ws + 256);
    uint2*  asg  = (uint2*)(ws + 262400);
    u16*    xb   = (u16*)(ws + 1179904);
    u16*    w1t  = (u16*)(ws + 17957120);
    u16*    w2t  = (u16*)(ws + 32637184);
    u16*    ybuf = (u16*)(ws + 47317248);

    hipMemsetAsync(cnt, 0, 32, stream);
    k_transpose_cvt<<<dim3(64, 16, 7), 256, 0, stream>>>(W1, w1t, 512, 2048);
    k_transpose_cvt<<<dim3(16, 64, 7), 256, 0, stream>>>(W2, w2t, 2048, 512);
    k_gate<<<4096, 256, 0, stream>>>(x, wg, xb, cnt, asg, rec);
    k_expert<<<dim3(256, 7), 512, 0, stream>>>(xb, w1t, w2t, b1, b2, cnt, asg, ybuf);
    k_final<<<8192, 256, 0, stream>>>(x, rec, ybuf, (float*)d_out);
}

// Round 4
// 693.323 us; speedup vs baseline: 1.5373x; 1.5373x over previous
//
#include <hip/hip_runtime.h>
#include <stdint.h>

#define EPS_VAL 2.220446049250313e-16f

typedef unsigned short u16;
typedef __bf16 bf16x8 __attribute__((ext_vector_type(8)));
typedef float f32x4 __attribute__((ext_vector_type(4)));

static __device__ __forceinline__ u16 f2bf(float v) {
    __bf16 b = (__bf16)v;
    return __builtin_bit_cast(u16, b);
}
static __device__ __forceinline__ float bf2f(u16 u) {
    __bf16 b = __builtin_bit_cast(__bf16, u);
    return (float)b;
}

// ---------------- transpose + convert: in [R][C] f32 -> out [C][R] bf16 ----------------
__global__ void k_transpose_cvt(const float* __restrict__ in, u16* __restrict__ out,
                                int R, int C) {
    __shared__ float t[32][33];
    const float* ip = in + (size_t)blockIdx.z * R * C;
    u16* op = out + (size_t)blockIdx.z * R * C;
    int tx = threadIdx.x & 31, ty = threadIdx.x >> 5;
    int c = blockIdx.x * 32 + tx;
    #pragma unroll
    for (int i = 0; i < 4; ++i) {
        int r = blockIdx.y * 32 + ty + i * 8;
        t[ty + i * 8][tx] = ip[(size_t)r * C + c];
    }
    __syncthreads();
    int r2 = blockIdx.y * 32 + tx;
    #pragma unroll
    for (int i = 0; i < 4; ++i) {
        int c2 = blockIdx.x * 32 + ty + i * 8;
        op[(size_t)c2 * R + r2] = f2bf(t[tx][ty + i * 8]);
    }
}

// ------- gating (fused x->bf16): logits, top-2, softmax, expert lists, xb -------
__global__ void k_gate(const float* __restrict__ x, const float* __restrict__ wg,
                       u16* __restrict__ xb, int* __restrict__ cnt,
                       uint2* __restrict__ asg, float4* __restrict__ rec) {
    int row  = blockIdx.x * 4 + (threadIdx.x >> 6);
    int lane = threadIdx.x & 63;
    const float4* px = (const float4*)(x + (size_t)row * 512) + lane * 2;
    float4 v0 = px[0], v1 = px[1];
    union { u16 h[8]; uint4 u; } o;
    o.h[0]=f2bf(v0.x); o.h[1]=f2bf(v0.y); o.h[2]=f2bf(v0.z); o.h[3]=f2bf(v0.w);
    o.h[4]=f2bf(v1.x); o.h[5]=f2bf(v1.y); o.h[6]=f2bf(v1.z); o.h[7]=f2bf(v1.w);
    ((uint4*)(xb + (size_t)row * 512))[lane] = o.u;

    float xv[8] = {v0.x, v0.y, v0.z, v0.w, v1.x, v1.y, v1.z, v1.w};
    float a0=0,a1=0,a2=0,a3=0,a4=0,a5=0,a6=0,a7=0;
    const float4* wp = (const float4*)wg + (size_t)lane * 16;
    #pragma unroll
    for (int j = 0; j < 8; ++j) {
        float4 wa = wp[j * 2], wb = wp[j * 2 + 1];
        float v = xv[j];
        a0 += v*wa.x; a1 += v*wa.y; a2 += v*wa.z; a3 += v*wa.w;
        a4 += v*wb.x; a5 += v*wb.y; a6 += v*wb.z; a7 += v*wb.w;
    }
    #pragma unroll
    for (int off = 32; off; off >>= 1) {
        a0 += __shfl_xor(a0, off); a1 += __shfl_xor(a1, off);
        a2 += __shfl_xor(a2, off); a3 += __shfl_xor(a3, off);
        a4 += __shfl_xor(a4, off); a5 += __shfl_xor(a5, off);
        a6 += __shfl_xor(a6, off); a7 += __shfl_xor(a7, off);
    }
    if (lane == 0) {
        float v[8] = {a0,a1,a2,a3,a4,a5,a6,a7};
        int i0 = 0;
        #pragma unroll
        for (int e = 1; e < 8; ++e) if (v[e] > v[i0]) i0 = e;
        int i1 = (i0 == 0) ? 1 : 0;
        #pragma unroll
        for (int e = 0; e < 8; ++e) if (e != i0 && v[e] > v[i1]) i1 = e;
        float ex = expf(v[i1] - v[i0]);
        float g0 = 1.f / (1.f + ex), g1 = ex / (1.f + ex);
        rec[row] = make_float4(__int_as_float(i0), __int_as_float(i1), g0, g1);
        if (i0 != 7) {
            int p = atomicAdd(&cnt[i0], 1);
            asg[i0 * 16384 + p] = make_uint2((unsigned)(row << 1), __float_as_uint(g0));
        }
        if (i1 != 7) {
            int p = atomicAdd(&cnt[i1], 1);
            asg[i1 * 16384 + p] = make_uint2((unsigned)((row << 1) | 1), __float_as_uint(g1));
        }
    }
}

// ------- fused per-expert MLP: R1 tiling + double-buffered prefetch staging -------
// LDS byte map (total 154112):
//   A(buf) = buf*33280          : W1s [32][520] u16 (padded)
//   B(buf) = 66560 + buf*40960  : W2s [512][40] u16 (padded)
//   Xs staging aliases [0,66560) (= A0+A1); dead after xa hoist
//   HS = 148480 : Hs [64][40] u16 ; rsl @153600 ; gl @153856
__global__ __launch_bounds__(512) void k_expert(
    const u16* __restrict__ xb,
    const u16* __restrict__ w1t,   // [7][2048][512] bf16 (W1^T)
    const u16* __restrict__ w2t,   // [7][512][2048] bf16 (W2^T)
    const float* __restrict__ b1,
    const float* __restrict__ b2,
    const int* __restrict__ cnt,
    const uint2* __restrict__ asg,
    u16* __restrict__ ybuf)        // [2][16384][512] bf16
{
    __shared__ __attribute__((aligned(16))) char smem[154112];
    int*   rsl = (int*)(smem + 153600);
    float* gl  = (float*)(smem + 153856);

    const int e    = blockIdx.y;
    const int base = blockIdx.x * 64;
    const int ce   = cnt[e];
    if (base >= ce) return;

    const int tid = threadIdx.x;
    if (tid < 64) {
        int idx = base + tid;
        if (idx < ce) {
            uint2 a = asg[e * 16384 + idx];
            rsl[tid] = (int)a.x;
            gl[tid]  = __builtin_bit_cast(float, a.y);
        } else { rsl[tid] = -1; gl[tid] = 0.f; }
    }
    __syncthreads();

    // stage X rows (64 x 512 bf16) into [0,66560), padded rows of 1040 B
    for (int i = tid; i < 4096; i += 512) {
        int r = i >> 6, c = i & 63;
        int rs = rsl[r];
        const u16* src = xb + (size_t)((rs < 0) ? 0 : (rs >> 1)) * 512;
        *(uint4*)(smem + r * 1040 + c * 16) = *(const uint4*)(src + c * 8);
    }
    __syncthreads();

    const int w    = tid >> 6;     // 0..7
    const int lane = tid & 63;
    const int l16  = lane & 15;
    const int q    = lane >> 4;
    const int kb   = q * 8;
    const int rt   = (w >> 1) * 16;   // 4 row groups
    const int ct   = (w & 1) * 16;    // 2 h-col groups

    bf16x8 xa[16];
    #pragma unroll
    for (int kk = 0; kk < 16; ++kk)
        xa[kk] = *(const bf16x8*)(smem + (rt + l16) * 1040 + (kk * 32 + kb) * 2);
    __syncthreads();   // xa hoisted before chunk-0 staging overwrites Xs

    const u16* w1p = w1t + (size_t)e * 2048 * 512;
    const u16* w2p = w2t + (size_t)e * 512 * 2048;

    // prologue: stage chunk 0 into buffers A0/B0 directly
    #pragma unroll
    for (int it = 0; it < 4; ++it) {
        int i = it * 512 + tid, r = i >> 6, c = i & 63;
        *(uint4*)(smem + r * 1040 + c * 16) =
            *(const uint4*)(w1p + (size_t)r * 512 + c * 8);
    }
    #pragma unroll
    for (int it = 0; it < 4; ++it) {
        int i = it * 512 + tid, d = i >> 2, p = i & 3;
        *(uint4*)(smem + 66560 + d * 80 + p * 16) =
            *(const uint4*)(w2p + (size_t)d * 2048 + p * 8);
    }
    float biasCur = b1[e * 2048 + ct + l16];
    __syncthreads();

    f32x4 acc[4][4];
    #pragma unroll
    for (int mt = 0; mt < 4; ++mt)
        #pragma unroll
        for (int nt = 0; nt < 4; ++nt) acc[mt][nt] = (f32x4){0.f, 0.f, 0.f, 0.f};

    for (int t = 0; t < 64; ++t) {
        const int cur = t & 1;
        const char* Ac = smem + cur * 33280;
        const char* Bc = smem + 66560 + cur * 40960;
        const int hcn = (t + 1) * 32;

        // issue prefetch loads for chunk t+1 (results consumed after phase 1)
        uint4 sW1[4], sW2[4];
        if (t < 63) {
            #pragma unroll
            for (int it = 0; it < 4; ++it) {
                int i = it * 512 + tid, r = i >> 6, c = i & 63;
                sW1[it] = *(const uint4*)(w1p + (size_t)(hcn + r) * 512 + c * 8);
            }
            #pragma unroll
            for (int it = 0; it < 4; ++it) {
                int i = it * 512 + tid, d = i >> 2, p = i & 3;
                sW2[it] = *(const uint4*)(w2p + (size_t)d * 2048 + hcn + p * 8);
            }
        }

        // phase 1: H tile (rt, ct), K=512 from xa regs
        f32x4 hacc = (f32x4){0.f, 0.f, 0.f, 0.f};
        #pragma unroll
        for (int kk = 0; kk < 16; ++kk) {
            bf16x8 bfr = *(const bf16x8*)(Ac + (ct + l16) * 1040 + (kk * 32 + kb) * 2);
            hacc = __builtin_amdgcn_mfma_f32_16x16x32_bf16(xa[kk], bfr, hacc, 0, 0, 0);
        }
        float biasNext = (t < 63) ? b1[e * 2048 + hcn + ct + l16] : 0.f;
        #pragma unroll
        for (int r = 0; r < 4; ++r) {
            float v = hacc[r] + biasCur;
            v = v > 0.f ? v : 0.f;
            *(u16*)(smem + 148480 + (rt + q * 4 + r) * 80 + (ct + l16) * 2) = f2bf(v);
        }
        biasCur = biasNext;

        // write prefetched chunk t+1 into the inactive buffers
        if (t < 63) {
            char* An = smem + (cur ^ 1) * 33280;
            char* Bn = smem + 66560 + (cur ^ 1) * 40960;
            #pragma unroll
            for (int it = 0; it < 4; ++it) {
                int i = it * 512 + tid, r = i >> 6, c = i & 63;
                *(uint4*)(An + r * 1040 + c * 16) = sW1[it];
            }
            #pragma unroll
            for (int it = 0; it < 4; ++it) {
                int i = it * 512 + tid, d = i >> 2, p = i & 3;
                *(uint4*)(Bn + d * 80 + p * 16) = sW2[it];
            }
        }
        __syncthreads();   // Hs ready + next-chunk staging visible

        // phase 2: acc += Hs(64x32) @ W2s(32 x 64-col slice per wave)
        bf16x8 af[4], bfm[4];
        #pragma unroll
        for (int mt = 0; mt < 4; ++mt)
            af[mt] = *(const bf16x8*)(smem + 148480 + (mt * 16 + l16) * 80 + q * 16);
        #pragma unroll
        for (int nt = 0; nt < 4; ++nt)
            bfm[nt] = *(const bf16x8*)(Bc + (w * 64 + nt * 16 + l16) * 80 + q * 16);
        #pragma unroll
        for (int mt = 0; mt < 4; ++mt)
            #pragma unroll
            for (int nt = 0; nt < 4; ++nt)
                acc[mt][nt] = __builtin_amdgcn_mfma_f32_16x16x32_bf16(
                    af[mt], bfm[nt], acc[mt][nt], 0, 0, 0);
        __syncthreads();   // all reads of [cur] and Hs complete
    }

    // epilogue: ybuf[slot][row][d] = bf16(g * (acc + b2))
    #pragma unroll
    for (int nt = 0; nt < 4; ++nt) {
        int d = w * 64 + nt * 16 + l16;
        float b2v = b2[e * 512 + d];
        #pragma unroll
        for (int mt = 0; mt < 4; ++mt) {
            #pragma unroll
            for (int r = 0; r < 4; ++r) {
                int m = mt * 16 + q * 4 + r;
                int rs = rsl[m];
                if (rs >= 0) {
                    ybuf[((size_t)(rs & 1) * 16384 + (rs >> 1)) * 512 + d] =
                        f2bf(gl[m] * (acc[mt][nt][r] + b2v));
                }
            }
        }
    }
}

// ---------------- final combine + EPS replacement ----------------
__global__ void k_final(const float* __restrict__ x, const float4* __restrict__ rec,
                        const u16* __restrict__ ybuf, float* __restrict__ out) {
    int i = blockIdx.x * 256 + threadIdx.x;
    int row = i >> 7;
    float4 r = rec[row];
    int e0 = __float_as_int(r.x), e1 = __float_as_int(r.y);
    float g7 = (e0 == 7) ? r.z : ((e1 == 7) ? r.w : 0.f);
    float4 xv = ((const float4*)x)[i];
    float o0 = g7 * xv.x, o1 = g7 * xv.y, o2 = g7 * xv.z, o3 = g7 * xv.w;
    size_t off = (size_t)i * 4;
    if (e0 != 7) {
        uint2 y = *(const uint2*)(ybuf + off);
        o0 += bf2f((u16)(y.x & 0xffff)); o1 += bf2f((u16)(y.x >> 16));
        o2 += bf2f((u16)(y.y & 0xffff)); o3 += bf2f((u16)(y.y >> 16));
    }
    if (e1 != 7) {
        uint2 y = *(const uint2*)(ybuf + 8388608 + off);
        o0 += bf2f((u16)(y.x & 0xffff)); o1 += bf2f((u16)(y.x >> 16));
        o2 += bf2f((u16)(y.y & 0xffff)); o3 += bf2f((u16)(y.y >> 16));
    }
    float4 res;
    res.x = (o0 == 0.f) ? EPS_VAL : o0;
    res.y = (o1 == 0.f) ? EPS_VAL : o1;
    res.z = (o2 == 0.f) ? EPS_VAL : o2;
    res.w = (o3 == 0.f) ? EPS_VAL : o3;
    ((float4*)out)[i] = res;
}

extern "C" void kernel_launch(void* const* d_in, const int* in_sizes, int n_in,
                              void* d_out, int out_size, void* d_ws, size_t ws_size,
                              hipStream_t stream) {
    const float* x  = (const float*)d_in[0];
    const float* wg = (const float*)d_in[1];
    const float* W1 = (const float*)d_in[2];
    const float* b1 = (const float*)d_in[3];
    const float* W2 = (const float*)d_in[4];
    const float* b2 = (const float*)d_in[5];

    char* ws = (char*)d_ws;
    int*    cnt  = (int*)ws;
    float4* rec  = (float4*)(ws + 256);
    uint2*  asg  = (uint2*)(ws + 262400);
    u16*    xb   = (u16*)(ws + 1179904);
    u16*    w1t  = (u16*)(ws + 17957120);
    u16*    w2t  = (u16*)(ws + 32637184);
    u16*    ybuf = (u16*)(ws + 47317248);

    hipMemsetAsync(cnt, 0, 32, stream);
    k_transpose_cvt<<<dim3(64, 16, 7), 256, 0, stream>>>(W1, w1t, 512, 2048);
    k_transpose_cvt<<<dim3(16, 64, 7), 256, 0, stream>>>(W2, w2t, 2048, 512);
    k_gate<<<4096, 256, 0, stream>>>(x, wg, xb, cnt, asg, rec);
    k_expert<<<dim3(256, 7), 512, 0, stream>>>(xb, w1t, w2t, b1, b2, cnt, asg, ybuf);
    k_final<<<8192, 256, 0, stream>>>(x, rec, ybuf, (float*)d_out);
}

// Round 5
// 493.073 us; speedup vs baseline: 2.1617x; 1.4061x over previous
//
#include <hip/hip_runtime.h>
#include <stdint.h>

#define EPS_VAL 2.220446049250313e-16f

typedef unsigned short u16;
typedef __bf16 bf16x8 __attribute__((ext_vector_type(8)));
typedef float f32x4 __attribute__((ext_vector_type(4)));

static __device__ __forceinline__ u16 f2bf(float v) {
    __bf16 b = (__bf16)v;
    return __builtin_bit_cast(u16, b);
}
static __device__ __forceinline__ float bf2f(u16 u) {
    __bf16 b = __builtin_bit_cast(__bf16, u);
    return (float)b;
}

// ---------------- transpose + convert: in [R][C] f32 -> out [C][R] bf16 ----------------
__global__ void k_transpose_cvt(const float* __restrict__ in, u16* __restrict__ out,
                                int R, int C) {
    __shared__ float t[32][33];
    const float* ip = in + (size_t)blockIdx.z * R * C;
    u16* op = out + (size_t)blockIdx.z * R * C;
    int tx = threadIdx.x & 31, ty = threadIdx.x >> 5;
    int c = blockIdx.x * 32 + tx;
    #pragma unroll
    for (int i = 0; i < 4; ++i) {
        int r = blockIdx.y * 32 + ty + i * 8;
        t[ty + i * 8][tx] = ip[(size_t)r * C + c];
    }
    __syncthreads();
    int r2 = blockIdx.y * 32 + tx;
    #pragma unroll
    for (int i = 0; i < 4; ++i) {
        int c2 = blockIdx.x * 32 + ty + i * 8;
        op[(size_t)c2 * R + r2] = f2bf(t[tx][ty + i * 8]);
    }
}

// ------- gating: 64 rows/block, LDS histogram + ranks, 7 global atomics/block -------
__global__ __launch_bounds__(1024) void k_gate(
    const float* __restrict__ x, const float* __restrict__ wg,
    u16* __restrict__ xb, int* __restrict__ cnt,
    uint2* __restrict__ asg, float4* __restrict__ rec) {
    __shared__ int hist[8];
    __shared__ int basep[8];
    __shared__ int   eA[64], eB[64], rA[64], rB[64];
    __shared__ float gA[64], gB[64];

    const int tid = threadIdx.x;
    if (tid < 8) hist[tid] = 0;
    __syncthreads();

    const int wv = tid >> 6, lane = tid & 63;
    #pragma unroll
    for (int it = 0; it < 4; ++it) {
        int rl  = it * 16 + wv;
        int row = blockIdx.x * 64 + rl;
        const float4* px = (const float4*)(x + (size_t)row * 512) + lane * 2;
        float4 v0 = px[0], v1 = px[1];
        union { u16 h[8]; uint4 u; } o;
        o.h[0]=f2bf(v0.x); o.h[1]=f2bf(v0.y); o.h[2]=f2bf(v0.z); o.h[3]=f2bf(v0.w);
        o.h[4]=f2bf(v1.x); o.h[5]=f2bf(v1.y); o.h[6]=f2bf(v1.z); o.h[7]=f2bf(v1.w);
        ((uint4*)(xb + (size_t)row * 512))[lane] = o.u;

        float xv[8] = {v0.x, v0.y, v0.z, v0.w, v1.x, v1.y, v1.z, v1.w};
        float a0=0,a1=0,a2=0,a3=0,a4=0,a5=0,a6=0,a7=0;
        const float4* wp = (const float4*)wg + (size_t)lane * 16;
        #pragma unroll
        for (int j = 0; j < 8; ++j) {
            float4 wa = wp[j * 2], wb = wp[j * 2 + 1];
            float v = xv[j];
            a0 += v*wa.x; a1 += v*wa.y; a2 += v*wa.z; a3 += v*wa.w;
            a4 += v*wb.x; a5 += v*wb.y; a6 += v*wb.z; a7 += v*wb.w;
        }
        #pragma unroll
        for (int off = 32; off; off >>= 1) {
            a0 += __shfl_xor(a0, off); a1 += __shfl_xor(a1, off);
            a2 += __shfl_xor(a2, off); a3 += __shfl_xor(a3, off);
            a4 += __shfl_xor(a4, off); a5 += __shfl_xor(a5, off);
            a6 += __shfl_xor(a6, off); a7 += __shfl_xor(a7, off);
        }
        if (lane == 0) {
            float v[8] = {a0,a1,a2,a3,a4,a5,a6,a7};
            int i0 = 0;
            #pragma unroll
            for (int e = 1; e < 8; ++e) if (v[e] > v[i0]) i0 = e;
            int i1 = (i0 == 0) ? 1 : 0;
            #pragma unroll
            for (int e = 0; e < 8; ++e) if (e != i0 && v[e] > v[i1]) i1 = e;
            float ex = expf(v[i1] - v[i0]);
            float g0 = 1.f / (1.f + ex), g1 = ex / (1.f + ex);
            rec[row] = make_float4(__int_as_float(i0), __int_as_float(i1), g0, g1);
            int r0 = (i0 != 7) ? atomicAdd(&hist[i0], 1) : -1;
            int r1 = (i1 != 7) ? atomicAdd(&hist[i1], 1) : -1;
            eA[rl] = i0; eB[rl] = i1; rA[rl] = r0; rB[rl] = r1;
            gA[rl] = g0; gB[rl] = g1;
        }
    }
    __syncthreads();
    if (tid < 7) basep[tid] = atomicAdd(&cnt[tid], hist[tid]);
    __syncthreads();
    if (tid < 64) {
        int row = blockIdx.x * 64 + tid;
        int i0 = eA[tid], i1 = eB[tid];
        if (i0 != 7)
            asg[i0 * 16384 + basep[i0] + rA[tid]] =
                make_uint2((unsigned)(row << 1), __float_as_uint(gA[tid]));
        if (i1 != 7)
            asg[i1 * 16384 + basep[i1] + rB[tid]] =
                make_uint2((unsigned)((row << 1) | 1), __float_as_uint(gB[tid]));
    }
}

// ------- fused per-expert MLP: XCD-pinned persistent workers, dbuf prefetch -------
// blocks dispatch round-robin over 8 XCDs (bid%8); expert e's weights (4MB) stay
// resident in its XCD's 4MB L2. XCD 7's 32 blocks act as extra workers.
// LDS byte map (total 154112):
//   A(buf) = buf*33280          : W1s [32][520] u16 (padded)
//   B(buf) = 66560 + buf*40960  : W2s [512][40] u16 (padded)
//   Xs staging aliases [0,66560); dead after xa hoist
//   HS = 148480 : Hs [64][40] u16 ; rsl @153600 ; gl @153856
__global__ __launch_bounds__(512) void k_expert(
    const u16* __restrict__ xb,
    const u16* __restrict__ w1t,   // [7][2048][512] bf16 (W1^T)
    const u16* __restrict__ w2t,   // [7][512][2048] bf16 (W2^T)
    const float* __restrict__ b1,
    const float* __restrict__ b2,
    const int* __restrict__ cnt,
    const uint2* __restrict__ asg,
    u16* __restrict__ ybuf)        // [2][16384][512] bf16
{
    __shared__ __attribute__((aligned(16))) char smem[154112];
    int*   rsl = (int*)(smem + 153600);
    float* gl  = (float*)(smem + 153856);

    const int bid = blockIdx.x;          // 0..255
    const int xcd = bid & 7, wk = bid >> 3;
    int e, worker;
    if (xcd < 7) { e = xcd; worker = wk; }
    else         { e = wk % 7; worker = 32 + wk / 7; }
    const int W = 32 + ((e < 4) ? 5 : 4);
    const int ce = cnt[e];

    const int tid  = threadIdx.x;
    const int w    = tid >> 6;
    const int lane = tid & 63;
    const int l16  = lane & 15;
    const int q    = lane >> 4;
    const int kb   = q * 8;
    const int rt   = (w >> 1) * 16;
    const int ct   = (w & 1) * 16;

    const u16* w1p = w1t + (size_t)e * 2048 * 512;
    const u16* w2p = w2t + (size_t)e * 512 * 2048;

    for (int b = worker; b * 64 < ce; b += W) {
        const int base = b * 64;
        __syncthreads();   // prior batch epilogue done reading rsl/gl
        if (tid < 64) {
            int idx = base + tid;
            if (idx < ce) {
                uint2 a = asg[e * 16384 + idx];
                rsl[tid] = (int)a.x;
                gl[tid]  = __builtin_bit_cast(float, a.y);
            } else { rsl[tid] = -1; gl[tid] = 0.f; }
        }
        __syncthreads();

        // stage X rows (64 x 512 bf16) into [0,66560), padded rows of 1040 B
        for (int i = tid; i < 4096; i += 512) {
            int r = i >> 6, c = i & 63;
            int rs = rsl[r];
            const u16* src = xb + (size_t)((rs < 0) ? 0 : (rs >> 1)) * 512;
            *(uint4*)(smem + r * 1040 + c * 16) = *(const uint4*)(src + c * 8);
        }
        __syncthreads();

        bf16x8 xa[16];
        #pragma unroll
        for (int kk = 0; kk < 16; ++kk)
            xa[kk] = *(const bf16x8*)(smem + (rt + l16) * 1040 + (kk * 32 + kb) * 2);
        __syncthreads();   // xa hoisted before chunk-0 staging overwrites Xs

        // prologue: stage chunk 0 into A0/B0
        #pragma unroll
        for (int it = 0; it < 4; ++it) {
            int i = it * 512 + tid, r = i >> 6, c = i & 63;
            *(uint4*)(smem + r * 1040 + c * 16) =
                *(const uint4*)(w1p + (size_t)r * 512 + c * 8);
        }
        #pragma unroll
        for (int it = 0; it < 4; ++it) {
            int i = it * 512 + tid, d = i >> 2, p = i & 3;
            *(uint4*)(smem + 66560 + d * 80 + p * 16) =
                *(const uint4*)(w2p + (size_t)d * 2048 + p * 8);
        }
        float biasCur = b1[e * 2048 + ct + l16];
        __syncthreads();

        f32x4 acc[4][4];
        #pragma unroll
        for (int mt = 0; mt < 4; ++mt)
            #pragma unroll
            for (int nt = 0; nt < 4; ++nt) acc[mt][nt] = (f32x4){0.f, 0.f, 0.f, 0.f};

        for (int t = 0; t < 64; ++t) {
            const int cur = t & 1;
            const char* Ac = smem + cur * 33280;
            const char* Bc = smem + 66560 + cur * 40960;
            const int hcn = (t + 1) * 32;

            // issue prefetch loads for chunk t+1
            uint4 sW1[4], sW2[4];
            if (t < 63) {
                #pragma unroll
                for (int it = 0; it < 4; ++it) {
                    int i = it * 512 + tid, r = i >> 6, c = i & 63;
                    sW1[it] = *(const uint4*)(w1p + (size_t)(hcn + r) * 512 + c * 8);
                }
                #pragma unroll
                for (int it = 0; it < 4; ++it) {
                    int i = it * 512 + tid, d = i >> 2, p = i & 3;
                    sW2[it] = *(const uint4*)(w2p + (size_t)d * 2048 + hcn + p * 8);
                }
            }

            // phase 1: H tile (rt, ct), K=512 from xa regs
            f32x4 hacc = (f32x4){0.f, 0.f, 0.f, 0.f};
            #pragma unroll
            for (int kk = 0; kk < 16; ++kk) {
                bf16x8 bfr = *(const bf16x8*)(Ac + (ct + l16) * 1040 + (kk * 32 + kb) * 2);
                hacc = __builtin_amdgcn_mfma_f32_16x16x32_bf16(xa[kk], bfr, hacc, 0, 0, 0);
            }
            float biasNext = (t < 63) ? b1[e * 2048 + hcn + ct + l16] : 0.f;
            #pragma unroll
            for (int r = 0; r < 4; ++r) {
                float v = hacc[r] + biasCur;
                v = v > 0.f ? v : 0.f;
                *(u16*)(smem + 148480 + (rt + q * 4 + r) * 80 + (ct + l16) * 2) = f2bf(v);
            }
            biasCur = biasNext;

            // write prefetched chunk t+1 into the inactive buffers
            if (t < 63) {
                char* An = smem + (cur ^ 1) * 33280;
                char* Bn = smem + 66560 + (cur ^ 1) * 40960;
                #pragma unroll
                for (int it = 0; it < 4; ++it) {
                    int i = it * 512 + tid, r = i >> 6, c = i & 63;
                    *(uint4*)(An + r * 1040 + c * 16) = sW1[it];
                }
                #pragma unroll
                for (int it = 0; it < 4; ++it) {
                    int i = it * 512 + tid, d = i >> 2, p = i & 3;
                    *(uint4*)(Bn + d * 80 + p * 16) = sW2[it];
                }
            }
            __syncthreads();   // Hs ready + next-chunk staging visible

            // phase 2: acc += Hs(64x32) @ W2s(32 x 64-col slice per wave)
            bf16x8 af[4], bfm[4];
            #pragma unroll
            for (int mt = 0; mt < 4; ++mt)
                af[mt] = *(const bf16x8*)(smem + 148480 + (mt * 16 + l16) * 80 + q * 16);
            #pragma unroll
            for (int nt = 0; nt < 4; ++nt)
                bfm[nt] = *(const bf16x8*)(Bc + (w * 64 + nt * 16 + l16) * 80 + q * 16);
            #pragma unroll
            for (int mt = 0; mt < 4; ++mt)
                #pragma unroll
                for (int nt = 0; nt < 4; ++nt)
                    acc[mt][nt] = __builtin_amdgcn_mfma_f32_16x16x32_bf16(
                        af[mt], bfm[nt], acc[mt][nt], 0, 0, 0);
            __syncthreads();   // all reads of [cur] and Hs complete
        }

        // epilogue: ybuf[slot][row][d] = bf16(g * (acc + b2))
        #pragma unroll
        for (int nt = 0; nt < 4; ++nt) {
            int d = w * 64 + nt * 16 + l16;
            float b2v = b2[e * 512 + d];
            #pragma unroll
            for (int mt = 0; mt < 4; ++mt) {
                #pragma unroll
                for (int r = 0; r < 4; ++r) {
                    int m = mt * 16 + q * 4 + r;
                    int rs = rsl[m];
                    if (rs >= 0) {
                        ybuf[((size_t)(rs & 1) * 16384 + (rs >> 1)) * 512 + d] =
                            f2bf(gl[m] * (acc[mt][nt][r] + b2v));
                    }
                }
            }
        }
    }
}

// ---------------- final combine + EPS replacement ----------------
__global__ void k_final(const float* __restrict__ x, const float4* __restrict__ rec,
                        const u16* __restrict__ ybuf, float* __restrict__ out) {
    int i = blockIdx.x * 256 + threadIdx.x;
    int row = i >> 7;
    float4 r = rec[row];
    int e0 = __float_as_int(r.x), e1 = __float_as_int(r.y);
    float g7 = (e0 == 7) ? r.z : ((e1 == 7) ? r.w : 0.f);
    float4 xv = ((const float4*)x)[i];
    float o0 = g7 * xv.x, o1 = g7 * xv.y, o2 = g7 * xv.z, o3 = g7 * xv.w;
    size_t off = (size_t)i * 4;
    if (e0 != 7) {
        uint2 y = *(const uint2*)(ybuf + off);
        o0 += bf2f((u16)(y.x & 0xffff)); o1 += bf2f((u16)(y.x >> 16));
        o2 += bf2f((u16)(y.y & 0xffff)); o3 += bf2f((u16)(y.y >> 16));
    }
    if (e1 != 7) {
        uint2 y = *(const uint2*)(ybuf + 8388608 + off);
        o0 += bf2f((u16)(y.x & 0xffff)); o1 += bf2f((u16)(y.x >> 16));
        o2 += bf2f((u16)(y.y & 0xffff)); o3 += bf2f((u16)(y.y >> 16));
    }
    float4 res;
    res.x = (o0 == 0.f) ? EPS_VAL : o0;
    res.y = (o1 == 0.f) ? EPS_VAL : o1;
    res.z = (o2 == 0.f) ? EPS_VAL : o2;
    res.w = (o3 == 0.f) ? EPS_VAL : o3;
    ((float4*)out)[i] = res;
}

extern "C" void kernel_launch(void* const* d_in, const int* in_sizes, int n_in,
                              void* d_out, int out_size, void* d_ws, size_t ws_size,
                              hipStream_t stream) {
    const float* x  = (const float*)d_in[0];
    const float* wg = (const float*)d_in[1];
    const float* W1 = (const float*)d_in[2];
    const float* b1 = (const float*)d_in[3];
    const float* W2 = (const float*)d_in[4];
    const float* b2 = (const float*)d_in[5];

    char* ws = (char*)d_ws;
    int*    cnt  = (int*)ws;
    float4* rec  = (float4*)(ws + 256);
    uint2*  asg  = (uint2*)(ws + 262400);
    u16*    xb   = (u16*)(ws + 1179904);
    u16*    w1t  = (u16*)(ws + 17957120);
    u16*    w2t  = (u16*)(ws + 32637184);
    u16*    ybuf = (u16*)(ws + 47317248);

    hipMemsetAsync(cnt, 0, 32, stream);
    k_transpose_cvt<<<dim3(64, 16, 7), 256, 0, stream>>>(W1, w1t, 512, 2048);
    k_transpose_cvt<<<dim3(16, 64, 7), 256, 0, stream>>>(W2, w2t, 2048, 512);
    k_gate<<<256, 1024, 0, stream>>>(x, wg, xb, cnt, asg, rec);
    k_expert<<<256, 512, 0, stream>>>(xb, w1t, w2t, b1, b2, cnt, asg, ybuf);
    k_final<<<8192, 256, 0, stream>>>(x, rec, ybuf, (float*)d_out);
}

// Round 6
// 392.299 us; speedup vs baseline: 2.7170x; 1.2569x over previous
//
#include <hip/hip_runtime.h>
#include <stdint.h>

#define EPS_VAL 2.220446049250313e-16f

typedef unsigned short u16;
typedef __bf16 bf16x8 __attribute__((ext_vector_type(8)));
typedef float f32x4 __attribute__((ext_vector_type(4)));

static __device__ __forceinline__ u16 f2bf(float v) {
    __bf16 b = (__bf16)v;
    return __builtin_bit_cast(u16, b);
}
static __device__ __forceinline__ float bf2f(u16 u) {
    __bf16 b = __builtin_bit_cast(__bf16, u);
    return (float)b;
}
static __device__ __forceinline__ void gll16(const void* g, void* l) {
    __builtin_amdgcn_global_load_lds(
        (const __attribute__((address_space(1))) unsigned int*)g,
        (__attribute__((address_space(3))) unsigned int*)l, 16, 0, 0);
}

// ---------------- transpose + convert: in [R][C] f32 -> out [C][R] bf16 ----------------
__global__ void k_transpose_cvt(const float* __restrict__ in, u16* __restrict__ out,
                                int R, int C) {
    __shared__ float t[32][33];
    const float* ip = in + (size_t)blockIdx.z * R * C;
    u16* op = out + (size_t)blockIdx.z * R * C;
    int tx = threadIdx.x & 31, ty = threadIdx.x >> 5;
    int c = blockIdx.x * 32 + tx;
    #pragma unroll
    for (int i = 0; i < 4; ++i) {
        int r = blockIdx.y * 32 + ty + i * 8;
        t[ty + i * 8][tx] = ip[(size_t)r * C + c];
    }
    __syncthreads();
    int r2 = blockIdx.y * 32 + tx;
    #pragma unroll
    for (int i = 0; i < 4; ++i) {
        int c2 = blockIdx.x * 32 + ty + i * 8;
        op[(size_t)c2 * R + r2] = f2bf(t[tx][ty + i * 8]);
    }
}

// ------- gating: 64 rows/block, LDS histogram + ranks, 7 global atomics/block -------
__global__ __launch_bounds__(1024) void k_gate(
    const float* __restrict__ x, const float* __restrict__ wg,
    u16* __restrict__ xb, int* __restrict__ cnt,
    uint2* __restrict__ asg, float4* __restrict__ rec) {
    __shared__ int hist[8];
    __shared__ int basep[8];
    __shared__ int   eA[64], eB[64], rA[64], rB[64];
    __shared__ float gA[64], gB[64];

    const int tid = threadIdx.x;
    if (tid < 8) hist[tid] = 0;
    __syncthreads();

    const int wv = tid >> 6, lane = tid & 63;
    #pragma unroll
    for (int it = 0; it < 4; ++it) {
        int rl  = it * 16 + wv;
        int row = blockIdx.x * 64 + rl;
        const float4* px = (const float4*)(x + (size_t)row * 512) + lane * 2;
        float4 v0 = px[0], v1 = px[1];
        union { u16 h[8]; uint4 u; } o;
        o.h[0]=f2bf(v0.x); o.h[1]=f2bf(v0.y); o.h[2]=f2bf(v0.z); o.h[3]=f2bf(v0.w);
        o.h[4]=f2bf(v1.x); o.h[5]=f2bf(v1.y); o.h[6]=f2bf(v1.z); o.h[7]=f2bf(v1.w);
        ((uint4*)(xb + (size_t)row * 512))[lane] = o.u;

        float xv[8] = {v0.x, v0.y, v0.z, v0.w, v1.x, v1.y, v1.z, v1.w};
        float a0=0,a1=0,a2=0,a3=0,a4=0,a5=0,a6=0,a7=0;
        const float4* wp = (const float4*)wg + (size_t)lane * 16;
        #pragma unroll
        for (int j = 0; j < 8; ++j) {
            float4 wa = wp[j * 2], wb = wp[j * 2 + 1];
            float v = xv[j];
            a0 += v*wa.x; a1 += v*wa.y; a2 += v*wa.z; a3 += v*wa.w;
            a4 += v*wb.x; a5 += v*wb.y; a6 += v*wb.z; a7 += v*wb.w;
        }
        #pragma unroll
        for (int off = 32; off; off >>= 1) {
            a0 += __shfl_xor(a0, off); a1 += __shfl_xor(a1, off);
            a2 += __shfl_xor(a2, off); a3 += __shfl_xor(a3, off);
            a4 += __shfl_xor(a4, off); a5 += __shfl_xor(a5, off);
            a6 += __shfl_xor(a6, off); a7 += __shfl_xor(a7, off);
        }
        if (lane == 0) {
            float v[8] = {a0,a1,a2,a3,a4,a5,a6,a7};
            int i0 = 0;
            #pragma unroll
            for (int e = 1; e < 8; ++e) if (v[e] > v[i0]) i0 = e;
            int i1 = (i0 == 0) ? 1 : 0;
            #pragma unroll
            for (int e = 0; e < 8; ++e) if (e != i0 && v[e] > v[i1]) i1 = e;
            float ex = expf(v[i1] - v[i0]);
            float g0 = 1.f / (1.f + ex), g1 = ex / (1.f + ex);
            rec[row] = make_float4(__int_as_float(i0), __int_as_float(i1), g0, g1);
            int r0 = (i0 != 7) ? atomicAdd(&hist[i0], 1) : -1;
            int r1 = (i1 != 7) ? atomicAdd(&hist[i1], 1) : -1;
            eA[rl] = i0; eB[rl] = i1; rA[rl] = r0; rB[rl] = r1;
            gA[rl] = g0; gB[rl] = g1;
        }
    }
    __syncthreads();
    if (tid < 7) basep[tid] = atomicAdd(&cnt[tid], hist[tid]);
    __syncthreads();
    if (tid < 64) {
        int row = blockIdx.x * 64 + tid;
        int i0 = eA[tid], i1 = eB[tid];
        if (i0 != 7)
            asg[i0 * 16384 + basep[i0] + rA[tid]] =
                make_uint2((unsigned)(row << 1), __float_as_uint(gA[tid]));
        if (i1 != 7)
            asg[i1 * 16384 + basep[i1] + rB[tid]] =
                make_uint2((unsigned)((row << 1) | 1), __float_as_uint(gB[tid]));
    }
}

// ------- fused per-expert MLP: XCD-pinned + work-stealing, gll dbuf pipeline -------
// LDS byte map (total 136704):
//   A(buf) = buf*32768          : W1s [32][512] u16, slot s stored at s^(row&7)
//   B(buf) = 65536 + buf*32768  : W2s [512][4 slots*16B], slot p stored at p^(d&3)
//   Xs staging aliases [0,65536) (rows [64][512] u16, same slot swizzle); dead after hoist
//   Hs @131072 : [64][40] u16 padded ; rsl @136192 ; gl @136448
__global__ __launch_bounds__(512) void k_expert(
    const u16* __restrict__ xb,
    const u16* __restrict__ w1t,   // [7][2048][512] bf16 (W1^T)
    const u16* __restrict__ w2t,   // [7][512][2048] bf16 (W2^T)
    const float* __restrict__ b1,
    const float* __restrict__ b2,
    const int* __restrict__ cnt,
    int* __restrict__ wrk,
    const uint2* __restrict__ asg,
    u16* __restrict__ ybuf)        // [2][16384][512] bf16
{
    __shared__ __attribute__((aligned(16))) char smem[136704];
    int*   rsl = (int*)(smem + 136192);
    float* gl  = (float*)(smem + 136448);
    __shared__ int bsh;

    const int bid = blockIdx.x;          // 0..255, bid&7 = XCD
    const int xcd = bid & 7, wk = bid >> 3;
    const int e = (xcd < 7) ? xcd : (wk % 7);
    const int ce = cnt[e];
    const int nb = (ce + 63) >> 6;

    const int tid  = threadIdx.x;
    const int w    = tid >> 6;
    const int lane = tid & 63;
    const int l16  = lane & 15;
    const int q    = lane >> 4;
    const int rt   = (w >> 1) * 16;
    const int ct   = (w & 1) * 16;

    const u16* w1p = w1t + (size_t)e * 2048 * 512;
    const u16* w2p = w2t + (size_t)e * 512 * 2048;

    for (;;) {
        if (tid == 0) bsh = atomicAdd(&wrk[e], 1);
        __syncthreads();                       // bsh visible; prior batch LDS reads done
        const int b = bsh;
        if (b >= nb) break;
        const int base = b * 64;

        if (tid < 64) {
            int idx = base + tid;
            if (idx < ce) {
                uint2 a = asg[e * 16384 + idx];
                rsl[tid] = (int)a.x;
                gl[tid]  = __builtin_bit_cast(float, a.y);
            } else { rsl[tid] = -1; gl[tid] = 0.f; }
        }
        __syncthreads();

        // stage X: wave w stages rows w*8..w*8+7 (1 KB each), swizzled source
        #pragma unroll
        for (int j = 0; j < 8; ++j) {
            int row = w * 8 + j;
            int rs = rsl[row];
            const u16* src = xb + (size_t)((rs < 0) ? 0 : (rs >> 1)) * 512;
            gll16(src + (lane ^ (row & 7)) * 8, smem + row * 1024);
        }
        __syncthreads();   // X resident (vmcnt drained)

        bf16x8 xa[16];
        {
            int row = rt + l16, rx = row & 7;
            #pragma unroll
            for (int kk = 0; kk < 16; ++kk)
                xa[kk] = *(const bf16x8*)(smem + row * 1024 + (((kk * 4 + q) ^ rx) * 16));
        }
        __syncthreads();   // hoist reads done before chunk-0 staging overwrites

        // prologue: stage chunk 0 into A0/B0
        #pragma unroll
        for (int i = 0; i < 4; ++i) {
            int row = w * 4 + i;
            gll16(w1p + (size_t)row * 512 + (lane ^ (row & 7)) * 8, smem + row * 1024);
        }
        #pragma unroll
        for (int i = 0; i < 4; ++i) {
            int d0 = (w * 4 + i) * 16;
            int d = d0 + (lane >> 2), p = lane & 3;
            gll16(w2p + (size_t)d * 2048 + ((p ^ (d & 3)) * 8), smem + 65536 + d0 * 64);
        }
        float biasCur = b1[e * 2048 + ct + l16];
        __syncthreads();   // chunk 0 resident

        f32x4 acc[4][4];
        #pragma unroll
        for (int mt = 0; mt < 4; ++mt)
            #pragma unroll
            for (int nt = 0; nt < 4; ++nt) acc[mt][nt] = (f32x4){0.f, 0.f, 0.f, 0.f};

        for (int t = 0; t < 64; ++t) {
            const int cur = t & 1;
            const char* Ac = smem + cur * 32768;
            const char* Bc = smem + 65536 + cur * 32768;
            const int hcn = (t + 1) * 32;

            // issue async staging for chunk t+1 into inactive buffers (no reg cost)
            if (t < 63) {
                char* An = smem + (cur ^ 1) * 32768;
                char* Bn = smem + 65536 + (cur ^ 1) * 32768;
                #pragma unroll
                for (int i = 0; i < 4; ++i) {
                    int row = w * 4 + i;
                    gll16(w1p + (size_t)(hcn + row) * 512 + (lane ^ (row & 7)) * 8,
                          An + row * 1024);
                }
                #pragma unroll
                for (int i = 0; i < 4; ++i) {
                    int d0 = (w * 4 + i) * 16;
                    int d = d0 + (lane >> 2), p = lane & 3;
                    gll16(w2p + (size_t)d * 2048 + hcn + ((p ^ (d & 3)) * 8),
                          Bn + d0 * 64);
                }
            }

            // phase 1: H tile (rt, ct), K=512 from xa regs vs W1 chunk
            f32x4 hacc = (f32x4){0.f, 0.f, 0.f, 0.f};
            {
                const int rx = l16 & 7;
                #pragma unroll
                for (int kk = 0; kk < 16; ++kk) {
                    bf16x8 bfr = *(const bf16x8*)(Ac + (ct + l16) * 1024 +
                                                  (((kk * 4 + q) ^ rx) * 16));
                    hacc = __builtin_amdgcn_mfma_f32_16x16x32_bf16(xa[kk], bfr, hacc, 0, 0, 0);
                }
            }
            float biasNext = (t < 63) ? b1[e * 2048 + hcn + ct + l16] : 0.f;
            #pragma unroll
            for (int r = 0; r < 4; ++r) {
                float v = hacc[r] + biasCur;
                v = v > 0.f ? v : 0.f;
                *(u16*)(smem + 131072 + (rt + q * 4 + r) * 80 + (ct + l16) * 2) = f2bf(v);
            }
            biasCur = biasNext;

            // mid-chunk barrier WITHOUT vmcnt drain: t+1 staging stays in flight
            asm volatile("s_waitcnt lgkmcnt(0)" ::: "memory");
            __builtin_amdgcn_s_barrier();
            __builtin_amdgcn_sched_barrier(0);

            // phase 2: acc += Hs(64x32) @ W2chunk(32 x 64-col slice per wave)
            bf16x8 af[4], bm[4];
            #pragma unroll
            for (int mt = 0; mt < 4; ++mt)
                af[mt] = *(const bf16x8*)(smem + 131072 + (mt * 16 + l16) * 80 + q * 16);
            #pragma unroll
            for (int nt = 0; nt < 4; ++nt) {
                int d = w * 64 + nt * 16 + l16;
                bm[nt] = *(const bf16x8*)(Bc + d * 64 + ((q ^ (d & 3)) * 16));
            }
            #pragma unroll
            for (int mt = 0; mt < 4; ++mt)
                #pragma unroll
                for (int nt = 0; nt < 4; ++nt)
                    acc[mt][nt] = __builtin_amdgcn_mfma_f32_16x16x32_bf16(
                        af[mt], bm[nt], acc[mt][nt], 0, 0, 0);
            __syncthreads();   // drains vmcnt: t+1 resident; orders reads before overwrite
        }

        // epilogue: ybuf[slot][row][d] = bf16(g * (acc + b2))
        #pragma unroll
        for (int nt = 0; nt < 4; ++nt) {
            int d = w * 64 + nt * 16 + l16;
            float b2v = b2[e * 512 + d];
            #pragma unroll
            for (int mt = 0; mt < 4; ++mt) {
                #pragma unroll
                for (int r = 0; r < 4; ++r) {
                    int m = mt * 16 + q * 4 + r;
                    int rs = rsl[m];
                    if (rs >= 0) {
                        ybuf[((size_t)(rs & 1) * 16384 + (rs >> 1)) * 512 + d] =
                            f2bf(gl[m] * (acc[mt][nt][r] + b2v));
                    }
                }
            }
        }
    }
}

// ---------------- final combine + EPS replacement ----------------
__global__ void k_final(const float* __restrict__ x, const float4* __restrict__ rec,
                        const u16* __restrict__ ybuf, float* __restrict__ out) {
    int i = blockIdx.x * 256 + threadIdx.x;
    int row = i >> 7;
    float4 r = rec[row];
    int e0 = __float_as_int(r.x), e1 = __float_as_int(r.y);
    float g7 = (e0 == 7) ? r.z : ((e1 == 7) ? r.w : 0.f);
    float4 xv = ((const float4*)x)[i];
    float o0 = g7 * xv.x, o1 = g7 * xv.y, o2 = g7 * xv.z, o3 = g7 * xv.w;
    size_t off = (size_t)i * 4;
    if (e0 != 7) {
        uint2 y = *(const uint2*)(ybuf + off);
        o0 += bf2f((u16)(y.x & 0xffff)); o1 += bf2f((u16)(y.x >> 16));
        o2 += bf2f((u16)(y.y & 0xffff)); o3 += bf2f((u16)(y.y >> 16));
    }
    if (e1 != 7) {
        uint2 y = *(const uint2*)(ybuf + 8388608 + off);
        o0 += bf2f((u16)(y.x & 0xffff)); o1 += bf2f((u16)(y.x >> 16));
        o2 += bf2f((u16)(y.y & 0xffff)); o3 += bf2f((u16)(y.y >> 16));
    }
    float4 res;
    res.x = (o0 == 0.f) ? EPS_VAL : o0;
    res.y = (o1 == 0.f) ? EPS_VAL : o1;
    res.z = (o2 == 0.f) ? EPS_VAL : o2;
    res.w = (o3 == 0.f) ? EPS_VAL : o3;
    ((float4*)out)[i] = res;
}

extern "C" void kernel_launch(void* const* d_in, const int* in_sizes, int n_in,
                              void* d_out, int out_size, void* d_ws, size_t ws_size,
                              hipStream_t stream) {
    const float* x  = (const float*)d_in[0];
    const float* wg = (const float*)d_in[1];
    const float* W1 = (const float*)d_in[2];
    const float* b1 = (const float*)d_in[3];
    const float* W2 = (const float*)d_in[4];
    const float* b2 = (const float*)d_in[5];

    char* ws = (char*)d_ws;
    int*    cnt  = (int*)ws;                  // 7 ints @0
    int*    wrk  = (int*)(ws + 32);           // 7 ints @32 (work-steal counters)
    float4* rec  = (float4*)(ws + 256);
    uint2*  asg  = (uint2*)(ws + 262400);
    u16*    xb   = (u16*)(ws + 1179904);
    u16*    w1t  = (u16*)(ws + 17957120);
    u16*    w2t  = (u16*)(ws + 32637184);
    u16*    ybuf = (u16*)(ws + 47317248);

    hipMemsetAsync(ws, 0, 256, stream);
    k_transpose_cvt<<<dim3(64, 16, 7), 256, 0, stream>>>(W1, w1t, 512, 2048);
    k_transpose_cvt<<<dim3(16, 64, 7), 256, 0, stream>>>(W2, w2t, 2048, 512);
    k_gate<<<256, 1024, 0, stream>>>(x, wg, xb, cnt, asg, rec);
    k_expert<<<256, 512, 0, stream>>>(xb, w1t, w2t, b1, b2, cnt, wrk, asg, ybuf);
    k_final<<<8192, 256, 0, stream>>>(x, rec, ybuf, (float*)d_out);
}